// Round 2
// baseline (495.982 us; speedup 1.0000x reference)
//
#include <hip/hip_runtime.h>
#include <math.h>

#define W_WORDS  4096
#define T_TOKENS 32768
#define N_EMBD   512
#define N_HIDDEN 2048
#define CAP      64   // max words per token list (Poisson mean ~16.4, P(>64) ~ 0)

// ---------------------------------------------------------------------------
// Tiled f32 GEMM: C[M,N] = A[M,K] @ B[K,N], with fused epilogue.
// MODE 0: exact GELU (0.5*x*(1+erf(x/sqrt(2))))   MODE 1: += Res[M,N]
// BM=BN=64, BK=16, 256 threads, 4x4 register tile per thread.
// ---------------------------------------------------------------------------
template <int MODE>
__global__ __launch_bounds__(256) void gemm_f32_kernel(
    const float* __restrict__ A, const float* __restrict__ B,
    const float* __restrict__ Res, float* __restrict__ C,
    int M, int N, int K)
{
    const int BM = 64, BN = 64, BK = 16, TM = 4, TN = 4;
    __shared__ float As[BK][BM];
    __shared__ float Bs[BK][BN];

    const int tid = threadIdx.x;
    const int tx  = tid & 15;   // N direction
    const int ty  = tid >> 4;   // M direction
    const int bm  = blockIdx.y * BM;
    const int bn  = blockIdx.x * BN;

    float acc[TM][TN];
#pragma unroll
    for (int i = 0; i < TM; ++i)
#pragma unroll
        for (int j = 0; j < TN; ++j) acc[i][j] = 0.0f;

    for (int k0 = 0; k0 < K; k0 += BK) {
        // A tile: As[k][m] = A[bm+r][k0+c] (transposed store), float4 loads
        {
            const int r = tid >> 2;          // 0..63
            const int c = (tid & 3) * 4;     // 0,4,8,12
            const float4 av = *(const float4*)(&A[(size_t)(bm + r) * K + k0 + c]);
            As[c + 0][r] = av.x;
            As[c + 1][r] = av.y;
            As[c + 2][r] = av.z;
            As[c + 3][r] = av.w;
            // B tile: Bs[k][n], row-major float4 loads
            const int rr = tid >> 4;         // 0..15
            const int cc = (tid & 15) * 4;   // 0..60
            const float4 bv = *(const float4*)(&B[(size_t)(k0 + rr) * N + bn + cc]);
            Bs[rr][cc + 0] = bv.x;
            Bs[rr][cc + 1] = bv.y;
            Bs[rr][cc + 2] = bv.z;
            Bs[rr][cc + 3] = bv.w;
        }
        __syncthreads();

#pragma unroll
        for (int k = 0; k < BK; ++k) {
            float ra[TM], rb[TN];
#pragma unroll
            for (int i = 0; i < TM; ++i) ra[i] = As[k][ty * TM + i];
#pragma unroll
            for (int j = 0; j < TN; ++j) rb[j] = Bs[k][tx * TN + j];
#pragma unroll
            for (int i = 0; i < TM; ++i)
#pragma unroll
                for (int j = 0; j < TN; ++j)
                    acc[i][j] = fmaf(ra[i], rb[j], acc[i][j]);
        }
        __syncthreads();
    }

#pragma unroll
    for (int i = 0; i < TM; ++i) {
        const int row = bm + ty * TM + i;
#pragma unroll
        for (int j = 0; j < TN; ++j) {
            const int col = bn + tx * TN + j;
            float v = acc[i][j];
            if (MODE == 0) {
                v = 0.5f * v * (1.0f + erff(v * 0.70710678118654752440f));
            } else {
                v += Res[(size_t)row * N + col];
            }
            C[(size_t)row * N + col] = v;
        }
    }
}

// ---------------------------------------------------------------------------
// Build per-token word lists from the INT32 mask [W, T] (numpy bool is pushed
// by the harness as int32: "integer -> const int*").
// Each thread scans 4 consecutive elements (fixed w, 4 consecutive t) = 16B.
// ---------------------------------------------------------------------------
__global__ __launch_bounds__(256) void build_lists_kernel(
    const int* __restrict__ mask,
    int* __restrict__ counts, unsigned short* __restrict__ lists)
{
    const size_t gid = (size_t)blockIdx.x * blockDim.x + threadIdx.x;
    const size_t e0  = gid * 4;                 // element index into [W*T]
    const int4 v = *(const int4*)(mask + e0);
    if ((v.x | v.y | v.z | v.w) == 0) return;

    const int w  = (int)(e0 >> 15);             // e0 / T_TOKENS
    const int t0 = (int)(e0 & (T_TOKENS - 1));

    const int vals[4] = {v.x, v.y, v.z, v.w};
#pragma unroll
    for (int q = 0; q < 4; ++q) {
        if (vals[q] != 0) {
            const int t = t0 + q;
            const int pos = atomicAdd(&counts[t], 1);
            if (pos < CAP) lists[(size_t)t * CAP + pos] = (unsigned short)w;
        }
    }
}

// ---------------------------------------------------------------------------
// Per-token gather-accumulate: x_new[t] = x[t] + sum_{w in list[t]} words[w].
// One wave (64 lanes) per token; lane handles 8 floats (2 x float4).
// ---------------------------------------------------------------------------
__global__ __launch_bounds__(256) void scatter_add_kernel(
    const float* __restrict__ x, const float* __restrict__ words,
    const int* __restrict__ counts, const unsigned short* __restrict__ lists,
    float* __restrict__ x_new)
{
    const int t    = blockIdx.x * 4 + (threadIdx.x >> 6);
    const int lane = threadIdx.x & 63;
    const size_t base = (size_t)t * N_EMBD + lane * 8;

    float4 a0 = *(const float4*)(x + base);
    float4 a1 = *(const float4*)(x + base + 4);

    const int cnt = min(counts[t], CAP);
    const unsigned short* lst = &lists[(size_t)t * CAP];

    for (int i = 0; i < cnt; ++i) {
        const int w = lst[i];
        const float* wr = words + (size_t)w * N_EMBD + lane * 8;
        const float4 b0 = *(const float4*)(wr);
        const float4 b1 = *(const float4*)(wr + 4);
        a0.x += b0.x; a0.y += b0.y; a0.z += b0.z; a0.w += b0.w;
        a1.x += b1.x; a1.y += b1.y; a1.z += b1.z; a1.w += b1.w;
    }

    *(float4*)(x_new + base)     = a0;
    *(float4*)(x_new + base + 4) = a1;
}

// ---------------------------------------------------------------------------
extern "C" void kernel_launch(void* const* d_in, const int* in_sizes, int n_in,
                              void* d_out, int out_size, void* d_ws, size_t ws_size,
                              hipStream_t stream)
{
    const float* in_words = (const float*)d_in[0];
    const float* x        = (const float*)d_in[1];
    const int*   mask     = (const int*)d_in[2];   // numpy bool -> int32 per harness
    const float* W_fc     = (const float*)d_in[3];
    const float* W_proj   = (const float*)d_in[4];

    float* out_words = (float*)d_out;                                // [4096, 512]
    float* out_x     = out_words + (size_t)W_WORDS * N_EMBD;         // [32768, 512]

    // workspace layout
    float*          h      = (float*)d_ws;                                        // 4096*2048*4 = 32 MiB
    int*            counts = (int*)((char*)d_ws + (size_t)W_WORDS * N_HIDDEN * 4); // 32768*4
    unsigned short* lists  = (unsigned short*)((char*)counts + (size_t)T_TOKENS * 4); // 32768*64*2 = 4 MiB

    // counts must be zero each call (harness does not re-poison between replays)
    hipMemsetAsync(counts, 0, (size_t)T_TOKENS * sizeof(int), stream);

    // GEMM1 + GELU: h = gelu(in_words @ W_fc)   [4096, 2048]
    {
        dim3 grid(N_HIDDEN / 64, W_WORDS / 64);
        gemm_f32_kernel<0><<<grid, 256, 0, stream>>>(in_words, W_fc, nullptr, h,
                                                     W_WORDS, N_HIDDEN, N_EMBD);
    }
    // GEMM2 + residual: words = h @ W_proj + in_words   [4096, 512]
    {
        dim3 grid(N_EMBD / 64, W_WORDS / 64);
        gemm_f32_kernel<1><<<grid, 256, 0, stream>>>(h, W_proj, in_words, out_words,
                                                     W_WORDS, N_EMBD, N_HIDDEN);
    }
    // Sparse list build from int32 mask
    {
        const size_t total_elems = (size_t)W_WORDS * T_TOKENS;      // 134,217,728
        const int blocks = (int)(total_elems / 4 / 256);            // 131,072
        build_lists_kernel<<<blocks, 256, 0, stream>>>(mask, counts, lists);
    }
    // Gather-accumulate into x_new
    {
        scatter_add_kernel<<<T_TOKENS / 4, 256, 0, stream>>>(x, out_words, counts,
                                                             lists, out_x);
    }
}

// Round 3
// 306.459 us; speedup vs baseline: 1.6184x; 1.6184x over previous
//
#include <hip/hip_runtime.h>
#include <hip/hip_bf16.h>
#include <math.h>

#define W_WORDS  4096
#define T_TOKENS 32768
#define N_EMBD   512
#define N_HIDDEN 2048
#define CAP      64   // max words per token (Binomial(4096,0.004): mean 16.4, 64 = +11.6 sigma)

typedef __attribute__((ext_vector_type(8))) short bf16x8;   // 8 bf16 = 4 VGPR (MFMA A/B frag)
typedef __attribute__((ext_vector_type(4))) float f32x4;    // MFMA C/D frag
typedef unsigned int u32;

#define GLOBAL_AS __attribute__((address_space(1)))
#define LDS_AS    __attribute__((address_space(3)))

// ---------------------------------------------------------------------------
// Elementwise f32 -> bf16, 8 elems/thread, vectorized loads/stores.
// ---------------------------------------------------------------------------
__global__ __launch_bounds__(256) void convert_to_bf16_kernel(
    const float* __restrict__ in, __hip_bfloat16* __restrict__ out)
{
    const size_t gid = (size_t)blockIdx.x * 256 + threadIdx.x;
    const float4 a = ((const float4*)in)[2 * gid];
    const float4 b = ((const float4*)in)[2 * gid + 1];
    union { __hip_bfloat16 t[8]; bf16x8 v; } u;
    u.t[0] = __float2bfloat16(a.x); u.t[1] = __float2bfloat16(a.y);
    u.t[2] = __float2bfloat16(a.z); u.t[3] = __float2bfloat16(a.w);
    u.t[4] = __float2bfloat16(b.x); u.t[5] = __float2bfloat16(b.y);
    u.t[6] = __float2bfloat16(b.z); u.t[7] = __float2bfloat16(b.w);
    *(bf16x8*)(out + 8 * gid) = u.v;
}

// ---------------------------------------------------------------------------
// Tiled transpose + convert: in f32 [R][C] -> out bf16 [C][R].
// 32x32 tiles, 256 threads (tx=0..31, ty=0..7, 4 rows per thread).
// ---------------------------------------------------------------------------
__global__ __launch_bounds__(256) void transpose_to_bf16_kernel(
    const float* __restrict__ in, __hip_bfloat16* __restrict__ out, int R, int C)
{
    __shared__ float tile[32][33];
    const int tx = threadIdx.x & 31;
    const int ty = threadIdx.x >> 5;
    const int r0 = blockIdx.y * 32;
    const int c0 = blockIdx.x * 32;
#pragma unroll
    for (int i = 0; i < 4; ++i) {
        const int r = ty + i * 8;
        tile[r][tx] = in[(size_t)(r0 + r) * C + c0 + tx];
    }
    __syncthreads();
#pragma unroll
    for (int i = 0; i < 4; ++i) {
        const int r = ty + i * 8;   // output row = input col
        out[(size_t)(c0 + r) * R + r0 + tx] = __float2bfloat16(tile[tx][r]);
    }
}

// ---------------------------------------------------------------------------
// bf16 MFMA GEMM: C[M,N] = A[M,K] @ B[K,N], B given TRANSPOSED as BT[N][K].
// BK=32, 256 threads = 4 waves in 2x2; wave tile (BM/2)x(BN/2);
// 16x16x32 MFMA fragments; global_load_lds width-16 staging (linear LDS).
// MODE 0: C = bf16(gelu_exact(acc))     MODE 1: C = f32(acc + Res)
// ---------------------------------------------------------------------------
template <int BM, int BN, int MODE>
__global__ __launch_bounds__(256) void gemm_bf16_mfma_kernel(
    const __hip_bfloat16* __restrict__ A,
    const __hip_bfloat16* __restrict__ BT,
    const float* __restrict__ Res,
    void* __restrict__ Cout,
    int M, int N, int K)
{
    constexpr int BK = 32;                    // 64 bytes per row
    constexpr int WM = BM / 2, WN = BN / 2;   // wave tile
    constexpr int FM = WM / 16, FN = WN / 16; // fragments per wave
    constexpr int NA = (BM * 64) / 4096;      // staging issues (256 thr x 16B)
    constexpr int NB = (BN * 64) / 4096;

    __shared__ __align__(16) char smem[(BM + BN) * BK * 2];
    char* As = smem;                 // [BM][32] bf16, 64 B rows, linear
    char* Bs = smem + BM * 64;       // [BN][32] bf16 (BT rows)

    const int tid  = threadIdx.x;
    const int lane = tid & 63;
    const int wid  = tid >> 6;
    const int wm   = wid >> 1, wn = wid & 1;

    const int bm = blockIdx.y * BM;
    const int bn = blockIdx.x * BN;

    f32x4 acc[FM][FN] = {};

    for (int k0 = 0; k0 < K; k0 += BK) {
        // ---- stage A tile: rows bm..bm+BM-1, k cols k0..k0+31 ----
#pragma unroll
        for (int a = 0; a < NA; ++a) {
            const int c    = a * 4 + wid;          // 1024-byte wave chunk
            const int loff = c * 1024 + lane * 16; // linear byte off in tile
            const int row  = loff >> 6;
            const int kb   = loff & 63;
            const __hip_bfloat16* src = A + (size_t)(bm + row) * K + k0 + (kb >> 1);
            __builtin_amdgcn_global_load_lds(
                (const GLOBAL_AS u32*)(const void*)src,
                (LDS_AS u32*)(void*)(As + c * 1024), 16, 0, 0);
        }
        // ---- stage B tile (BT rows = output cols) ----
#pragma unroll
        for (int b = 0; b < NB; ++b) {
            const int c    = b * 4 + wid;
            const int loff = c * 1024 + lane * 16;
            const int row  = loff >> 6;
            const int kb   = loff & 63;
            const __hip_bfloat16* src = BT + (size_t)(bn + row) * K + k0 + (kb >> 1);
            __builtin_amdgcn_global_load_lds(
                (const GLOBAL_AS u32*)(const void*)src,
                (LDS_AS u32*)(void*)(Bs + c * 1024), 16, 0, 0);
        }
        __syncthreads();

        // ---- fragments: contiguous 16B per lane (ds_read_b128) ----
        bf16x8 af[FM], bfq[FN];
#pragma unroll
        for (int i = 0; i < FM; ++i) {
            const int row = wm * WM + i * 16 + (lane & 15);
            af[i] = *(const bf16x8*)(As + row * 64 + (lane >> 4) * 16);
        }
#pragma unroll
        for (int j = 0; j < FN; ++j) {
            const int col = wn * WN + j * 16 + (lane & 15);
            bfq[j] = *(const bf16x8*)(Bs + col * 64 + (lane >> 4) * 16);
        }
#pragma unroll
        for (int i = 0; i < FM; ++i)
#pragma unroll
            for (int j = 0; j < FN; ++j)
                acc[i][j] = __builtin_amdgcn_mfma_f32_16x16x32_bf16(
                    af[i], bfq[j], acc[i][j], 0, 0, 0);
        __syncthreads();
    }

    // ---- epilogue: C/D layout col=lane&15, row=(lane>>4)*4+r ----
#pragma unroll
    for (int i = 0; i < FM; ++i) {
        const int row0 = bm + wm * WM + i * 16 + (lane >> 4) * 4;
#pragma unroll
        for (int j = 0; j < FN; ++j) {
            const int col = bn + wn * WN + j * 16 + (lane & 15);
#pragma unroll
            for (int r = 0; r < 4; ++r) {
                const int row = row0 + r;
                float v = acc[i][j][r];
                if (MODE == 0) {
                    v = 0.5f * v * (1.0f + erff(v * 0.70710678118654752440f));
                    ((__hip_bfloat16*)Cout)[(size_t)row * N + col] = __float2bfloat16(v);
                } else {
                    ((float*)Cout)[(size_t)row * N + col] =
                        v + Res[(size_t)row * N + col];
                }
            }
        }
    }
}

// ---------------------------------------------------------------------------
// Build per-token word lists from the INT32 mask [W, T].
// ---------------------------------------------------------------------------
__global__ __launch_bounds__(256) void build_lists_kernel(
    const int* __restrict__ mask,
    int* __restrict__ counts, unsigned short* __restrict__ lists)
{
    const size_t gid = (size_t)blockIdx.x * blockDim.x + threadIdx.x;
    const size_t e0  = gid * 4;
    const int4 v = *(const int4*)(mask + e0);
    if ((v.x | v.y | v.z | v.w) == 0) return;

    const int w  = (int)(e0 >> 15);
    const int t0 = (int)(e0 & (T_TOKENS - 1));

    const int vals[4] = {v.x, v.y, v.z, v.w};
#pragma unroll
    for (int q = 0; q < 4; ++q) {
        if (vals[q] != 0) {
            const int t = t0 + q;
            const int pos = atomicAdd(&counts[t], 1);
            if (pos < CAP) lists[(size_t)t * CAP + pos] = (unsigned short)w;
        }
    }
}

// ---------------------------------------------------------------------------
// Per-token gather-accumulate: x_new[t] = x[t] + sum_{w in list[t]} words[w].
// One wave per token; lane handles 8 floats.
// ---------------------------------------------------------------------------
__global__ __launch_bounds__(256) void scatter_add_kernel(
    const float* __restrict__ x, const float* __restrict__ words,
    const int* __restrict__ counts, const unsigned short* __restrict__ lists,
    float* __restrict__ x_new)
{
    const int t    = blockIdx.x * 4 + (threadIdx.x >> 6);
    const int lane = threadIdx.x & 63;
    const size_t base = (size_t)t * N_EMBD + lane * 8;

    float4 a0 = *(const float4*)(x + base);
    float4 a1 = *(const float4*)(x + base + 4);

    const int cnt = min(counts[t], CAP);
    const unsigned short* lst = &lists[(size_t)t * CAP];

    for (int i = 0; i < cnt; ++i) {
        const int w = lst[i];
        const float* wr = words + (size_t)w * N_EMBD + lane * 8;
        const float4 b0 = *(const float4*)(wr);
        const float4 b1 = *(const float4*)(wr + 4);
        a0.x += b0.x; a0.y += b0.y; a0.z += b0.z; a0.w += b0.w;
        a1.x += b1.x; a1.y += b1.y; a1.z += b1.z; a1.w += b1.w;
    }

    *(float4*)(x_new + base)     = a0;
    *(float4*)(x_new + base + 4) = a1;
}

// ---------------------------------------------------------------------------
extern "C" void kernel_launch(void* const* d_in, const int* in_sizes, int n_in,
                              void* d_out, int out_size, void* d_ws, size_t ws_size,
                              hipStream_t stream)
{
    const float* in_words = (const float*)d_in[0];
    const float* x        = (const float*)d_in[1];
    const int*   mask     = (const int*)d_in[2];   // numpy bool -> int32 per harness
    const float* W_fc     = (const float*)d_in[3];
    const float* W_proj   = (const float*)d_in[4];

    float* out_words = (float*)d_out;                        // [4096, 512]
    float* out_x     = out_words + (size_t)W_WORDS * N_EMBD; // [32768, 512]

    // workspace layout (bytes)
    char* ws = (char*)d_ws;
    __hip_bfloat16* words_bf = (__hip_bfloat16*)(ws);                    //  4 MiB [4096][512]
    __hip_bfloat16* WfcT     = (__hip_bfloat16*)(ws + (4u << 20));       //  2 MiB [2048][512]
    __hip_bfloat16* WprojT   = (__hip_bfloat16*)(ws + (6u << 20));       //  2 MiB [512][2048]
    __hip_bfloat16* h_bf     = (__hip_bfloat16*)(ws + (8u << 20));       // 16 MiB [4096][2048]
    int*            counts   = (int*)(ws + (24u << 20));                 // 128 KiB
    unsigned short* lists    = (unsigned short*)(ws + (24u << 20) + (T_TOKENS * 4)); // 4 MiB

    hipMemsetAsync(counts, 0, (size_t)T_TOKENS * sizeof(int), stream);

    // f32 -> bf16 conversions / transposes
    convert_to_bf16_kernel<<<(W_WORDS * N_EMBD) / (8 * 256), 256, 0, stream>>>(
        in_words, words_bf);
    transpose_to_bf16_kernel<<<dim3(N_HIDDEN / 32, N_EMBD / 32), 256, 0, stream>>>(
        W_fc, WfcT, N_EMBD, N_HIDDEN);     // [512][2048] -> [2048][512]
    transpose_to_bf16_kernel<<<dim3(N_EMBD / 32, N_HIDDEN / 32), 256, 0, stream>>>(
        W_proj, WprojT, N_HIDDEN, N_EMBD); // [2048][512] -> [512][2048]

    // GEMM1 + GELU: h_bf = gelu(words_bf @ W_fc)  [4096, 2048]
    gemm_bf16_mfma_kernel<128, 128, 0>
        <<<dim3(N_HIDDEN / 128, W_WORDS / 128), 256, 0, stream>>>(
            words_bf, WfcT, nullptr, h_bf, W_WORDS, N_HIDDEN, N_EMBD);

    // GEMM2 + residual: out_words = h_bf @ W_proj + in_words  [4096, 512]
    gemm_bf16_mfma_kernel<128, 64, 1>
        <<<dim3(N_EMBD / 64, W_WORDS / 128), 256, 0, stream>>>(
            h_bf, WprojT, in_words, out_words, W_WORDS, N_EMBD, N_HIDDEN);

    // Sparse list build from int32 mask
    build_lists_kernel<<<(int)((size_t)W_WORDS * T_TOKENS / 4 / 256), 256, 0, stream>>>(
        mask, counts, lists);

    // Gather-accumulate into x_new
    scatter_add_kernel<<<T_TOKENS / 4, 256, 0, stream>>>(
        x, out_words, counts, lists, out_x);
}